// Round 3
// baseline (245.621 us; speedup 1.0000x reference)
//
#include <hip/hip_runtime.h>

typedef __attribute__((ext_vector_type(8))) _Float16 half8;
typedef __attribute__((ext_vector_type(4))) _Float16 half4;
typedef __attribute__((ext_vector_type(4))) float f32x4;

#define MFMA_K32(a, b, c) __builtin_amdgcn_mfma_f32_16x16x32_f16((a), (b), (c), 0, 0, 0)
#define MFMA_K16(a, b, c) __builtin_amdgcn_mfma_f32_16x16x16f16((a), (b), (c), 0, 0, 0)

// async global->LDS, 16B per lane; LDS dest = wave-uniform base + lane*16
__device__ inline void async16(const _Float16* g, _Float16* l) {
    __builtin_amdgcn_global_load_lds(
        (const __attribute__((address_space(1))) void*)g,
        (__attribute__((address_space(3))) void*)l, 16, 0, 0);
}

// ---------------------------------------------------------------------------
// B=32, S=512, Dm=768, H=12, d=64, M=16384.
// probs = (s*0.125+5)^2; probs /= (rowsum+1e-10); probs *= mask; ctx = probs@V
// Folded: ctx = (sum_k w_k * (mask_k v_k)) / (sum_k w_k + 1e-10)
// Q is pre-scaled by 0.125 at the GEMM epilogue, so attn uses s = q.k + 5.
// ---------------------------------------------------------------------------

// Kernel 0: X f32 -> f16
__global__ __launch_bounds__(256) void xcast(const float* __restrict__ X,
                                             _Float16* __restrict__ Xh)
{
    size_t idx = ((size_t)blockIdx.x * 256 + threadIdx.x) * 8;
    float4 a = *(const float4*)(X + idx);
    float4 c = *(const float4*)(X + idx + 4);
    half8 hv;
    hv[0] = (_Float16)a.x; hv[1] = (_Float16)a.y;
    hv[2] = (_Float16)a.z; hv[3] = (_Float16)a.w;
    hv[4] = (_Float16)c.x; hv[5] = (_Float16)c.y;
    hv[6] = (_Float16)c.z; hv[7] = (_Float16)c.w;
    *(half8*)(Xh + idx) = hv;
}

// Kernel 1: weights transpose+cast: Wt[n][k] = (f16) W[k][n]
__global__ __launch_bounds__(256) void wcast_kernel(
    const float* __restrict__ W0, const float* __restrict__ W1,
    const float* __restrict__ W2,
    _Float16* __restrict__ T0, _Float16* __restrict__ T1,
    _Float16* __restrict__ T2)
{
    int z = blockIdx.z;
    const float* W = (z == 0) ? W0 : (z == 1) ? W1 : W2;
    _Float16* T = (z == 0) ? T0 : (z == 1) ? T1 : T2;
    __shared__ float tile[32][33];
    int n0 = blockIdx.x * 32, k0 = blockIdx.y * 32;
    int tx = threadIdx.x & 31, ty = threadIdx.x >> 5;
#pragma unroll
    for (int r = 0; r < 4; ++r)
        tile[ty + 8 * r][tx] = W[(size_t)(k0 + ty + 8 * r) * 768 + n0 + tx];
    __syncthreads();
#pragma unroll
    for (int r = 0; r < 4; ++r)
        T[(size_t)(n0 + ty + 8 * r) * 768 + k0 + tx] =
            (_Float16)tile[tx][ty + 8 * r];
}

// ---------------------------------------------------------------------------
// Kernel 2: fused QKV GEMM, C[16384 x 2304] over z = n/768.
// (round-0 proven structure: 128x128 tile, 256 thr, 32 KB LDS -> 4+ blocks/CU;
// phase-pipelined 512-thr variant measured SLOWER at K=768 — keep this.)
// BK=64 (12 K-iters). XOR swizzle on 16B chunks: LDS chunk j of a row holds
// global chunk j ^ (row&7); readers use slot = g ^ (row&7) -> 2-way (free).
// Q out pre-scaled 0.125. V out transposed [B,H,64,S], premasked.
// ---------------------------------------------------------------------------
__global__ __launch_bounds__(256) void qkv_gemm(
    const _Float16* __restrict__ Xh,
    const _Float16* __restrict__ W0, const _Float16* __restrict__ W1,
    const _Float16* __restrict__ W2,
    const float* __restrict__ b0, const float* __restrict__ b1,
    const float* __restrict__ b2,
    const float* __restrict__ mask,
    _Float16* __restrict__ Qo, _Float16* __restrict__ Ko,
    _Float16* __restrict__ Vo)
{
    int z = blockIdx.y / 6;
    int n0 = (blockIdx.y % 6) * 128;
    int m0 = blockIdx.x * 128;
    const _Float16* Wt = (z == 0) ? W0 : (z == 1) ? W1 : W2;
    const float* bias = (z == 0) ? b0 : (z == 1) ? b1 : b2;

    __shared__ __attribute__((aligned(16))) _Float16 As[128 * 64];  // 16 KB
    __shared__ __attribute__((aligned(16))) _Float16 Bs[128 * 64];  // 16 KB

    int t = threadIdx.x;
    int wave = t >> 6, lane = t & 63, quad = lane >> 4, l16 = lane & 15;
    int wm = (wave & 1) * 64, wn = (wave >> 1) * 64;

    // staging: chunk index c = slot*256 + t; row = c>>3, LDS slot j = c&7,
    // global chunk g = j ^ (row&7).  (slot*256 doesn't change row&7 or j.)
    int srow = t >> 3;               // 0..31 (row advances +32 per slot)
    int sg = (t & 7) ^ (srow & 7);   // global chunk this thread fetches

    const _Float16* gA = Xh + (size_t)(m0 + srow) * 768 + sg * 8;
    const _Float16* gB = Wt + (size_t)(n0 + srow) * 768 + sg * 8;
    _Float16* lA = As + t * 8;
    _Float16* lB = Bs + t * 8;

    f32x4 acc[4][4] = {};

    for (int k0 = 0; k0 < 768; k0 += 64) {
#pragma unroll
        for (int q = 0; q < 4; ++q) {
            async16(gA + (size_t)q * 32 * 768 + k0, lA + q * 2048);
            async16(gB + (size_t)q * 32 * 768 + k0, lB + q * 2048);
        }
        __syncthreads();  // drains vmcnt -> tiles staged
#pragma unroll
        for (int ks = 0; ks < 2; ++ks) {
            half8 af[4], bf[4];
#pragma unroll
            for (int i = 0; i < 4; ++i) {
                int row = wm + i * 16 + l16;
                af[i] = *(const half8*)&As[row * 64 +
                                           (((ks << 2) + quad) ^ (row & 7)) * 8];
            }
#pragma unroll
            for (int j = 0; j < 4; ++j) {
                int row = wn + j * 16 + l16;
                bf[j] = *(const half8*)&Bs[row * 64 +
                                           (((ks << 2) + quad) ^ (row & 7)) * 8];
            }
#pragma unroll
            for (int i = 0; i < 4; ++i)
#pragma unroll
                for (int j = 0; j < 4; ++j)
                    acc[i][j] = MFMA_K32(af[i], bf[j], acc[i][j]);
        }
        __syncthreads();
    }

    // epilogue: C row = wm+i*16+quad*4+r ; col = wn+j*16+l16
    float mk[4][4];
    if (z == 2) {
#pragma unroll
        for (int i = 0; i < 4; ++i) {
            int mbase = m0 + wm + i * 16 + quad * 4;
            int bb = mbase >> 9, s = mbase & 511;
#pragma unroll
            for (int r = 0; r < 4; ++r)
                mk[i][r] = mask[(size_t)bb * 512 + s + r];
        }
    }
#pragma unroll
    for (int j = 0; j < 4; ++j) {
        int n = n0 + wn + j * 16 + l16;
        float bv = bias[n];
        int hh = n >> 6, d = n & 63;
#pragma unroll
        for (int i = 0; i < 4; ++i) {
            int mbase = m0 + wm + i * 16 + quad * 4;
            int bb = mbase >> 9, s = mbase & 511;
            if (z == 0) {
                // Q, pre-scaled by 0.125 (score scale folded in)
#pragma unroll
                for (int r = 0; r < 4; ++r) {
                    size_t off = (((size_t)(bb * 12 + hh)) * 512 + s + r) * 64 + d;
                    Qo[off] = (_Float16)((acc[i][j][r] + bv) * 0.125f);
                }
            } else if (z == 1) {
#pragma unroll
                for (int r = 0; r < 4; ++r) {
                    size_t off = (((size_t)(bb * 12 + hh)) * 512 + s + r) * 64 + d;
                    Ko[off] = (_Float16)(acc[i][j][r] + bv);
                }
            } else {
                // V^T [B,H,64,S], premasked; regs = consecutive tokens -> 8B store
                half4 pk;
#pragma unroll
                for (int r = 0; r < 4; ++r)
                    pk[r] = (_Float16)((acc[i][j][r] + bv) * mk[i][r]);
                size_t off = (((size_t)(bb * 12 + hh)) * 64 + d) * 512 + s;
                *(half4*)&Vo[off] = pk;
            }
        }
    }
}

// ---------------------------------------------------------------------------
// Kernel 3: power-law attention — DMA-staged (global_load_lds) double buffer.
// Block = 4 waves x 64 queries (256 q), grid (2, H, B) = 768 blocks = 3/CU.
// v2 (reg-staged dbuf) still paid a VGPR round-trip (16 staged regs live
// across compute -> pressure) + an LDS-write phase per tile.  v3: stage via
// async16 DMA with XOR-swizzled SOURCE chunks (rule #21: linear LDS dest,
// pre-swizzled global address; read with slot = chunk ^ (row&7)) — the exact
// pattern measured conflict-free in qkv_gemm.  LDS 45 -> 32 KB, -16 VGPR,
// no write-late phase.  Prefetch depth 1: issue next tile's 4 DMAs before
// compute; the tile-end barrier's vmcnt drain lands ~1000 cyc later (free).
// Per 64-key tile: S^T = K Q^T via 16x16x32 MFMA (C: row=key, col=query).
//   Lane holds P[q=l16][k=quad*4+r] == A-fragment of 16x16x16 f16 MFMA.
//   rowsum via MFMA with ones B-frag; ctx += P @ V via 16x16x16 MFMA.
// V premasked; rowsum over unmasked w == reference semantics.
// ---------------------------------------------------------------------------
__global__ __launch_bounds__(256) void attn_kernel(
    const _Float16* __restrict__ Q, const _Float16* __restrict__ K,
    const _Float16* __restrict__ Vt, float* __restrict__ out)
{
    __shared__ __attribute__((aligned(16))) _Float16 Ks[2][64 * 64];  // 16 KB
    __shared__ __attribute__((aligned(16))) _Float16 Vs[2][64 * 64];  // 16 KB

    int t = threadIdx.x;
    int wave = t >> 6, lane = t & 63, quad = lane >> 4, l16 = lane & 15;
    int h = blockIdx.y, b = blockIdx.z;
    size_t bh = (size_t)b * 12 + h;
    const _Float16* Qp = Q + bh * (512 * 64);
    const _Float16* Kp = K + bh * (512 * 64);
    const _Float16* Vp = Vt + bh * (64 * 512);
    int qbase = blockIdx.x * 256 + wave * 64;

    // Q fragments (B-operand layout == row-major half8 at [query][d])
    half8 qf[4][2];
#pragma unroll
    for (int i = 0; i < 4; ++i)
#pragma unroll
        for (int ks = 0; ks < 2; ++ks)
            qf[i][ks] = *(const half8*)(Qp + (size_t)(qbase + i * 16 + l16) * 64 +
                                        ks * 32 + quad * 8);

    f32x4 ctx[4][4] = {};
    f32x4 rsum[4] = {};
    const half4 ones = {(_Float16)1.f, (_Float16)1.f, (_Float16)1.f, (_Float16)1.f};

    // DMA staging geometry: rows of 64 halves = 8 chunks of 16B.
    // shot s (0/1) covers rows s*32..s*32+31; thread t -> row srow0+s*32,
    // LDS slot j = t&7 holds global chunk j ^ (row&7)  (row&7 == srow0&7).
    int srow0 = t >> 3;                       // 0..31
    int sg = (t & 7) ^ (srow0 & 7);
    const _Float16* kg = Kp + (size_t)srow0 * 64 + sg * 8;   // +kt*4096 +shot*2048
    const _Float16* vg = Vp + (size_t)srow0 * 512 + sg * 8;  // +kt*64  +shot*16384
    _Float16* lK = (_Float16*)Ks + t * 8;     // +buf*4096 +shot*2048
    _Float16* lV = (_Float16*)Vs + t * 8;

    // prologue: tile 0 -> buf 0
    async16(kg, lK);
    async16(kg + 2048, lK + 2048);
    async16(vg, lV);
    async16(vg + 16384, lV + 2048);
    __syncthreads();   // drains vmcnt(0): tile 0 staged

    int pswz = quad ^ (l16 & 7);              // K frag chunk-slot (kf1 = ^4)
    int vc   = (quad >> 1) ^ (l16 & 7);       // V frag: chunk 2*kb + (quad>>1)
    int vsub = (quad & 1) * 4;

    for (int kt = 0; kt < 8; ++kt) {
        int c = kt & 1;
        if (kt < 7) {
            // issue next tile's DMAs NOW; tile-end barrier drain is ~1000 cyc
            // later -> HBM latency hidden under compute
            int nb = 1 - c;
            async16(kg + (kt + 1) * 4096, lK + nb * 4096);
            async16(kg + (kt + 1) * 4096 + 2048, lK + nb * 4096 + 2048);
            async16(vg + (kt + 1) * 64, lV + nb * 4096);
            async16(vg + (kt + 1) * 64 + 16384, lV + nb * 4096 + 2048);
        }

        const _Float16* Kc = Ks[c];
        const _Float16* Vc = Vs[c];
        __builtin_amdgcn_s_setprio(1);
#pragma unroll
        for (int kb = 0; kb < 4; ++kb) {
            int krow = kb * 16 + l16;
            half8 kf0 = *(const half8*)&Kc[krow * 64 + pswz * 8];
            half8 kf1 = *(const half8*)&Kc[krow * 64 + (pswz ^ 4) * 8];
            // phase A: all QK^T MFMAs (independent chains across i)
            f32x4 sc[4];
#pragma unroll
            for (int i = 0; i < 4; ++i) {
                f32x4 s0 = {0.f, 0.f, 0.f, 0.f};
                s0 = MFMA_K32(kf0, qf[i][0], s0);
                sc[i] = MFMA_K32(kf1, qf[i][1], s0);
            }
            // phase B: VALU transform  w = (s+5)^2  (Q pre-scaled by 0.125)
            half4 pA[4];
#pragma unroll
            for (int i = 0; i < 4; ++i) {
#pragma unroll
                for (int r = 0; r < 4; ++r) {
                    float s = sc[i][r] + 5.0f;
                    pA[i][r] = (_Float16)(s * s);
                }
            }
            // phase C: rowsum MFMAs
#pragma unroll
            for (int i = 0; i < 4; ++i)
                rsum[i] = MFMA_K16(pA[i], ones, rsum[i]);
            // phase D: PV  (V frag: row d = n*16+l16, keys kb*16+quad*4)
#pragma unroll
            for (int n = 0; n < 4; ++n) {
                half4 vf = *(const half4*)&Vc[(n * 16 + l16) * 64 +
                                              ((2 * kb + (quad >> 1)) ^ (l16 & 7)) * 8 +
                                              vsub];
#pragma unroll
                for (int i = 0; i < 4; ++i)
                    ctx[i][n] = MFMA_K16(pA[i], vf, ctx[i][n]);
            }
        }
        __builtin_amdgcn_s_setprio(0);
        __syncthreads();  // one barrier/tile: drains vmcnt -> buf(1-c) staged;
                          // all waves done reading buf(c) before kt+2 reuses it
    }

    // epilogue: rsum reg r and ctx reg r both live on C row = quad*4+r
#pragma unroll
    for (int i = 0; i < 4; ++i) {
        f32x4 inv;
#pragma unroll
        for (int r = 0; r < 4; ++r)
            inv[r] = 1.0f / (rsum[i][r] + 1e-10f);
#pragma unroll
        for (int n = 0; n < 4; ++n)
#pragma unroll
            for (int r = 0; r < 4; ++r) {
                int q = qbase + i * 16 + quad * 4 + r;
                int d = n * 16 + l16;
                out[((size_t)b * 512 + q) * 768 + h * 64 + d] =
                    ctx[i][n][r] * inv[r];
            }
    }
}

// ---------------------------------------------------------------------------
extern "C" void kernel_launch(void* const* d_in, const int* in_sizes, int n_in,
                              void* d_out, int out_size, void* d_ws, size_t ws_size,
                              hipStream_t stream)
{
    const float* hs   = (const float*)d_in[0];
    const float* mask = (const float*)d_in[1];
    const float* Wq   = (const float*)d_in[2];
    const float* bq   = (const float*)d_in[3];
    const float* Wk   = (const float*)d_in[4];
    const float* bk   = (const float*)d_in[5];
    const float* Wv   = (const float*)d_in[6];
    const float* bv   = (const float*)d_in[7];
    float* out = (float*)d_out;

    char* ws = (char*)d_ws;
    _Float16* Wtq = (_Float16*)ws;            // 3 x 768*768 halves
    _Float16* Wtk = Wtq + 768 * 768;
    _Float16* Wtv = Wtk + 768 * 768;
    _Float16* Qb  = Wtv + 768 * 768;          // 3 x 16384*768 halves
    _Float16* Kb  = Qb + 16384 * 768;
    _Float16* Vb  = Kb + 16384 * 768;
    // ws use ~79 MB. Xh scratch lives in d_out (Xh 25 MB, dead before attn).
    _Float16* Xh = (_Float16*)d_out;

    xcast<<<dim3(6144), 256, 0, stream>>>(hs, Xh);
    wcast_kernel<<<dim3(24, 24, 3), 256, 0, stream>>>(Wq, Wk, Wv, Wtq, Wtk, Wtv);
    qkv_gemm<<<dim3(128, 18), 256, 0, stream>>>(Xh, Wtq, Wtk, Wtv,
                                                bq, bk, bv, mask, Qb, Kb, Vb);
    attn_kernel<<<dim3(2, 12, 32), 256, 0, stream>>>(Qb, Kb, Vb, out);
}

// Round 4
// 234.094 us; speedup vs baseline: 1.0492x; 1.0492x over previous
//
#include <hip/hip_runtime.h>

typedef __attribute__((ext_vector_type(8))) _Float16 half8;
typedef __attribute__((ext_vector_type(4))) _Float16 half4;
typedef __attribute__((ext_vector_type(4))) float f32x4;

#define MFMA_K32(a, b, c) __builtin_amdgcn_mfma_f32_16x16x32_f16((a), (b), (c), 0, 0, 0)
#define MFMA_K16(a, b, c) __builtin_amdgcn_mfma_f32_16x16x16f16((a), (b), (c), 0, 0, 0)

// async global->LDS, 16B per lane; LDS dest = wave-uniform base + lane*16
__device__ inline void async16(const _Float16* g, _Float16* l) {
    __builtin_amdgcn_global_load_lds(
        (const __attribute__((address_space(1))) void*)g,
        (__attribute__((address_space(3))) void*)l, 16, 0, 0);
}

// ---------------------------------------------------------------------------
// B=32, S=512, Dm=768, H=12, d=64, M=16384.
// probs = (s*0.125+5)^2; probs /= (rowsum+1e-10); probs *= mask; ctx = probs@V
// Folded: ctx = (sum_k w_k * (mask_k v_k)) / (sum_k w_k + 1e-10)
// Q is pre-scaled by 0.125 at the GEMM epilogue, so attn uses s = q.k + 5.
// ---------------------------------------------------------------------------

// Kernel 0: fused prep — X f32->f16 cast (blocks 0..6143) and weight
// transpose+cast (blocks 6144..7871).  One launch instead of two.
__global__ __launch_bounds__(256) void prep_kernel(
    const float* __restrict__ X, _Float16* __restrict__ Xh,
    const float* __restrict__ W0, const float* __restrict__ W1,
    const float* __restrict__ W2,
    _Float16* __restrict__ T0, _Float16* __restrict__ T1,
    _Float16* __restrict__ T2)
{
    __shared__ float tile[32][33];
    int bid = blockIdx.x;
    if (bid < 6144) {
        size_t idx = ((size_t)bid * 256 + threadIdx.x) * 8;
        float4 a = *(const float4*)(X + idx);
        float4 c = *(const float4*)(X + idx + 4);
        half8 hv;
        hv[0] = (_Float16)a.x; hv[1] = (_Float16)a.y;
        hv[2] = (_Float16)a.z; hv[3] = (_Float16)a.w;
        hv[4] = (_Float16)c.x; hv[5] = (_Float16)c.y;
        hv[6] = (_Float16)c.z; hv[7] = (_Float16)c.w;
        *(half8*)(Xh + idx) = hv;
    } else {
        int id = bid - 6144;                 // 1728 = 3 x 24 x 24
        int z = id / 576; id -= z * 576;
        int n0 = (id / 24) * 32, k0 = (id % 24) * 32;
        const float* W = (z == 0) ? W0 : (z == 1) ? W1 : W2;
        _Float16* T = (z == 0) ? T0 : (z == 1) ? T1 : T2;
        int tx = threadIdx.x & 31, ty = threadIdx.x >> 5;
#pragma unroll
        for (int r = 0; r < 4; ++r)
            tile[ty + 8 * r][tx] = W[(size_t)(k0 + ty + 8 * r) * 768 + n0 + tx];
        __syncthreads();
#pragma unroll
        for (int r = 0; r < 4; ++r)
            T[(size_t)(n0 + ty + 8 * r) * 768 + k0 + tx] =
                (_Float16)tile[tx][ty + 8 * r];
    }
}

// ---------------------------------------------------------------------------
// Kernel 2: fused QKV GEMM, C[16384 x 2304] over z = n/768.
// (round-0 proven K-loop: 128x128 tile, 256 thr, 32 KB LDS -> 4+ blocks/CU.)
// BK=64 (12 K-iters). XOR swizzle on 16B chunks: LDS chunk j of a row holds
// global chunk j ^ (row&7); readers use slot = g ^ (row&7) -> 2-way (free).
//
// EPILOGUE FIX (this round): WRITE_SIZE measured 103 MB vs 72 ideal, and
// Q/K paths issued 64 scalar 2B stores/thread (reg r = token row -> nothing
// packs).  The MFMA is operand-symmetric, so for z<2 we SWAP af/bf sources
// (af <- W tile, bf <- X tile), computing C^T: now reg r = d-dim -> half4
// packs 4 consecutive d -> 16x 8B stores with 32B segments (same as V path).
// K-loop and LDS addressing untouched (identical geometry, pointer swap).
// Q out pre-scaled 0.125. V out transposed [B,H,64,S], premasked.
// ---------------------------------------------------------------------------
__global__ __launch_bounds__(256) void qkv_gemm(
    const _Float16* __restrict__ Xh,
    const _Float16* __restrict__ W0, const _Float16* __restrict__ W1,
    const _Float16* __restrict__ W2,
    const float* __restrict__ b0, const float* __restrict__ b1,
    const float* __restrict__ b2,
    const float* __restrict__ mask,
    _Float16* __restrict__ Qo, _Float16* __restrict__ Ko,
    _Float16* __restrict__ Vo)
{
    int z = blockIdx.y / 6;
    int n0 = (blockIdx.y % 6) * 128;
    int m0 = blockIdx.x * 128;
    const _Float16* Wt = (z == 0) ? W0 : (z == 1) ? W1 : W2;
    const float* bias = (z == 0) ? b0 : (z == 1) ? b1 : b2;

    __shared__ __attribute__((aligned(16))) _Float16 As[128 * 64];  // 16 KB
    __shared__ __attribute__((aligned(16))) _Float16 Bs[128 * 64];  // 16 KB

    int t = threadIdx.x;
    int wave = t >> 6, lane = t & 63, quad = lane >> 4, l16 = lane & 15;
    int wm = (wave & 1) * 64, wn = (wave >> 1) * 64;

    // staging: chunk index c = slot*256 + t; row = c>>3, LDS slot j = c&7,
    // global chunk g = j ^ (row&7).  (slot*256 doesn't change row&7 or j.)
    int srow = t >> 3;               // 0..31 (row advances +32 per slot)
    int sg = (t & 7) ^ (srow & 7);   // global chunk this thread fetches

    const _Float16* gA = Xh + (size_t)(m0 + srow) * 768 + sg * 8;
    const _Float16* gB = Wt + (size_t)(n0 + srow) * 768 + sg * 8;
    _Float16* lA = As + t * 8;
    _Float16* lB = Bs + t * 8;

    // operand-role swap: for z<2, C rows = W-dim (so r packs over d at the
    // store); for z==2 keep C rows = token (V wants [d][token] with r=token).
    const _Float16* Pa = (z == 2) ? As : Bs;   // feeds af (C rows)
    const _Float16* Pb = (z == 2) ? Bs : As;   // feeds bf (C cols)

    f32x4 acc[4][4] = {};

    for (int k0 = 0; k0 < 768; k0 += 64) {
#pragma unroll
        for (int q = 0; q < 4; ++q) {
            async16(gA + (size_t)q * 32 * 768 + k0, lA + q * 2048);
            async16(gB + (size_t)q * 32 * 768 + k0, lB + q * 2048);
        }
        __syncthreads();  // drains vmcnt -> tiles staged
#pragma unroll
        for (int ks = 0; ks < 2; ++ks) {
            half8 af[4], bf[4];
#pragma unroll
            for (int i = 0; i < 4; ++i) {
                int row = wm + i * 16 + l16;
                af[i] = *(const half8*)&Pa[row * 64 +
                                           (((ks << 2) + quad) ^ (row & 7)) * 8];
            }
#pragma unroll
            for (int j = 0; j < 4; ++j) {
                int row = wn + j * 16 + l16;
                bf[j] = *(const half8*)&Pb[row * 64 +
                                           (((ks << 2) + quad) ^ (row & 7)) * 8];
            }
#pragma unroll
            for (int i = 0; i < 4; ++i)
#pragma unroll
                for (int j = 0; j < 4; ++j)
                    acc[i][j] = MFMA_K32(af[i], bf[j], acc[i][j]);
        }
        __syncthreads();
    }

    if (z != 2) {
        // C^T: row = n-dim = n0 + wm + i*16 + quad*4 + r (4 consecutive d,
        // head-aligned since quad*4+r < 16); col = token = m0 + wn + j*16 + l16.
#pragma unroll
        for (int i = 0; i < 4; ++i) {
            int nbase = n0 + wm + i * 16 + quad * 4;
            int hh = nbase >> 6, dbase = nbase & 63;
            float4 bv4 = *(const float4*)&bias[nbase];
#pragma unroll
            for (int j = 0; j < 4; ++j) {
                int token = m0 + wn + j * 16 + l16;
                int bb = token >> 9, s = token & 511;
                half4 pk;
                if (z == 0) {
#pragma unroll
                    for (int r = 0; r < 4; ++r)
                        pk[r] = (_Float16)((acc[i][j][r] + ((const float*)&bv4)[r]) * 0.125f);
                } else {
#pragma unroll
                    for (int r = 0; r < 4; ++r)
                        pk[r] = (_Float16)(acc[i][j][r] + ((const float*)&bv4)[r]);
                }
                size_t off = (((size_t)(bb * 12 + hh)) * 512 + s) * 64 + dbase;
                if (z == 0) *(half4*)&Qo[off] = pk;
                else        *(half4*)&Ko[off] = pk;
            }
        }
    } else {
        // V (unswapped): row = token = m0+wm+i*16+quad*4+r, col = n0+wn+j*16+l16
        float mk[4][4];
#pragma unroll
        for (int i = 0; i < 4; ++i) {
            int mbase = m0 + wm + i * 16 + quad * 4;
            int bb = mbase >> 9, s = mbase & 511;
#pragma unroll
            for (int r = 0; r < 4; ++r)
                mk[i][r] = mask[(size_t)bb * 512 + s + r];
        }
#pragma unroll
        for (int j = 0; j < 4; ++j) {
            int n = n0 + wn + j * 16 + l16;
            float bv = bias[n];
            int hh = n >> 6, d = n & 63;
#pragma unroll
            for (int i = 0; i < 4; ++i) {
                int mbase = m0 + wm + i * 16 + quad * 4;
                int bb = mbase >> 9, s = mbase & 511;
                // V^T [B,H,64,S], premasked; regs = consecutive tokens -> 8B store
                half4 pk;
#pragma unroll
                for (int r = 0; r < 4; ++r)
                    pk[r] = (_Float16)((acc[i][j][r] + bv) * mk[i][r]);
                size_t off = (((size_t)(bb * 12 + hh)) * 64 + d) * 512 + s;
                *(half4*)&Vo[off] = pk;
            }
        }
    }
}

// ---------------------------------------------------------------------------
// Kernel 3: power-law attention, P-in-registers — reg-staged double buffer
// (round-2 variant, best measured; the DMA-staged rewrite regressed 5 µs).
// Block = 4 waves x 64 queries (256 q), grid (2, H, B) = 768 blocks
// (3 blocks/CU resident: LDS 45 KB -> 3 fit; 12 waves/CU; ALL blocks
// co-resident in one shot).
// 2-deep LDS buffers; next tile's global loads ISSUE before compute,
// LDS write lands after compute (vmcnt hidden under ~1300 cyc of MFMA);
// ONE barrier per tile (write(t+1) targets the other buffer than compute(t)).
// Per 64-key tile: S^T = K Q^T via 16x16x32 MFMA (C: row=key, col=query).
//   Lane holds P[q=l16][k=quad*4+r] == A-fragment of 16x16x16 f16 MFMA.
//   rowsum via MFMA with ones B-frag; ctx += P @ V via 16x16x16 MFMA.
// V premasked; rowsum over unmasked w == reference semantics.
// ---------------------------------------------------------------------------
__global__ __launch_bounds__(256) void attn_kernel(
    const _Float16* __restrict__ Q, const _Float16* __restrict__ K,
    const _Float16* __restrict__ Vt, float* __restrict__ out)
{
    __shared__ __attribute__((aligned(16))) _Float16 Ks[2][64 * 88];  // 22.5 KB
    __shared__ __attribute__((aligned(16))) _Float16 Vs[2][64 * 88];  // 22.5 KB

    int t = threadIdx.x;
    int wave = t >> 6, lane = t & 63, quad = lane >> 4, l16 = lane & 15;
    int h = blockIdx.y, b = blockIdx.z;
    size_t bh = (size_t)b * 12 + h;
    const _Float16* Qp = Q + bh * (512 * 64);
    const _Float16* Kp = K + bh * (512 * 64);
    const _Float16* Vp = Vt + bh * (64 * 512);
    int qbase = blockIdx.x * 256 + wave * 64;

    // Q fragments (B-operand layout == row-major half8 at [query][d])
    half8 qf[4][2];
#pragma unroll
    for (int i = 0; i < 4; ++i)
#pragma unroll
        for (int ks = 0; ks < 2; ++ks)
            qf[i][ks] = *(const half8*)(Qp + (size_t)(qbase + i * 16 + l16) * 64 +
                                        ks * 32 + quad * 8);

    f32x4 ctx[4][4] = {};
    f32x4 rsum[4] = {};
    const half4 ones = {(_Float16)1.f, (_Float16)1.f, (_Float16)1.f, (_Float16)1.f};

    int srow = t >> 2, spart = (t & 3) * 16;  // 4 threads/row, 16 halves each
    const _Float16* kgb = Kp + (size_t)srow * 64 + spart;   // + kt*64*64
    const _Float16* vgb = Vp + (size_t)srow * 512 + spart;  // + kt*64

    // prologue: tile 0 -> buf 0
    half8 ka0 = *(const half8*)(kgb);
    half8 ka1 = *(const half8*)(kgb + 8);
    half8 va0 = *(const half8*)(vgb);
    half8 va1 = *(const half8*)(vgb + 8);
    *(half8*)&Ks[0][srow * 88 + spart] = ka0;
    *(half8*)&Ks[0][srow * 88 + spart + 8] = ka1;
    *(half8*)&Vs[0][srow * 88 + spart] = va0;
    *(half8*)&Vs[0][srow * 88 + spart + 8] = va1;
    __syncthreads();

    for (int kt = 0; kt < 8; ++kt) {
        int c = kt & 1;
        if (kt < 7) {
            // issue next tile's loads NOW; their vmcnt-wait sits after compute
            size_t ko = (size_t)(kt + 1) * 64;
            ka0 = *(const half8*)(kgb + ko * 64);
            ka1 = *(const half8*)(kgb + ko * 64 + 8);
            va0 = *(const half8*)(vgb + ko);
            va1 = *(const half8*)(vgb + ko + 8);
        }

        __builtin_amdgcn_s_setprio(1);
#pragma unroll
        for (int kb = 0; kb < 4; ++kb) {
            half8 kf0 = *(const half8*)&Ks[c][(kb * 16 + l16) * 88 + quad * 8];
            half8 kf1 = *(const half8*)&Ks[c][(kb * 16 + l16) * 88 + 32 + quad * 8];
            // phase A: all QK^T MFMAs (independent chains across i)
            f32x4 sc[4];
#pragma unroll
            for (int i = 0; i < 4; ++i) {
                f32x4 s0 = {0.f, 0.f, 0.f, 0.f};
                s0 = MFMA_K32(kf0, qf[i][0], s0);
                sc[i] = MFMA_K32(kf1, qf[i][1], s0);
            }
            // phase B: VALU transform  w = (s+5)^2  (Q pre-scaled by 0.125)
            half4 pA[4];
#pragma unroll
            for (int i = 0; i < 4; ++i) {
#pragma unroll
                for (int r = 0; r < 4; ++r) {
                    float s = sc[i][r] + 5.0f;
                    pA[i][r] = (_Float16)(s * s);
                }
            }
            // phase C: rowsum MFMAs
#pragma unroll
            for (int i = 0; i < 4; ++i)
                rsum[i] = MFMA_K16(pA[i], ones, rsum[i]);
            // phase D: PV
#pragma unroll
            for (int n = 0; n < 4; ++n) {
                half4 vf = *(const half4*)&Vs[c][(n * 16 + l16) * 88 + kb * 16 + quad * 4];
#pragma unroll
                for (int i = 0; i < 4; ++i)
                    ctx[i][n] = MFMA_K16(pA[i], vf, ctx[i][n]);
            }
        }
        __builtin_amdgcn_s_setprio(0);

        if (kt < 7) {
            // write-late: loads issued ~1300 cycles ago -> vmcnt wait is free
            *(half8*)&Ks[1 - c][srow * 88 + spart] = ka0;
            *(half8*)&Ks[1 - c][srow * 88 + spart + 8] = ka1;
            *(half8*)&Vs[1 - c][srow * 88 + spart] = va0;
            *(half8*)&Vs[1 - c][srow * 88 + spart + 8] = va1;
        }
        __syncthreads();  // single barrier per tile: buf(1-c) writes published,
                          // and all waves done reading buf(c) before it's
                          // overwritten in iteration kt+2
    }

    // epilogue: rsum reg r and ctx reg r both live on C row = quad*4+r
#pragma unroll
    for (int i = 0; i < 4; ++i) {
        f32x4 inv;
#pragma unroll
        for (int r = 0; r < 4; ++r)
            inv[r] = 1.0f / (rsum[i][r] + 1e-10f);
#pragma unroll
        for (int n = 0; n < 4; ++n)
#pragma unroll
            for (int r = 0; r < 4; ++r) {
                int q = qbase + i * 16 + quad * 4 + r;
                int d = n * 16 + l16;
                out[((size_t)b * 512 + q) * 768 + h * 64 + d] =
                    ctx[i][n][r] * inv[r];
            }
    }
}

// ---------------------------------------------------------------------------
extern "C" void kernel_launch(void* const* d_in, const int* in_sizes, int n_in,
                              void* d_out, int out_size, void* d_ws, size_t ws_size,
                              hipStream_t stream)
{
    const float* hs   = (const float*)d_in[0];
    const float* mask = (const float*)d_in[1];
    const float* Wq   = (const float*)d_in[2];
    const float* bq   = (const float*)d_in[3];
    const float* Wk   = (const float*)d_in[4];
    const float* bk   = (const float*)d_in[5];
    const float* Wv   = (const float*)d_in[6];
    const float* bv   = (const float*)d_in[7];
    float* out = (float*)d_out;

    char* ws = (char*)d_ws;
    _Float16* Wtq = (_Float16*)ws;            // 3 x 768*768 halves
    _Float16* Wtk = Wtq + 768 * 768;
    _Float16* Wtv = Wtk + 768 * 768;
    _Float16* Qb  = Wtv + 768 * 768;          // 3 x 16384*768 halves
    _Float16* Kb  = Qb + 16384 * 768;
    _Float16* Vb  = Kb + 16384 * 768;
    // ws use ~79 MB. Xh scratch lives in d_out (Xh 25 MB, dead before attn).
    _Float16* Xh = (_Float16*)d_out;

    prep_kernel<<<dim3(7872), 256, 0, stream>>>(hs, Xh, Wq, Wk, Wv,
                                                Wtq, Wtk, Wtv);
    qkv_gemm<<<dim3(128, 18), 256, 0, stream>>>(Xh, Wtq, Wtk, Wtv,
                                                bq, bk, bv, mask, Qb, Kb, Vb);
    attn_kernel<<<dim3(2, 12, 32), 256, 0, stream>>>(Qb, Kb, Vb, out);
}